// Round 1
// baseline (987.030 us; speedup 1.0000x reference)
//
#include <hip/hip_runtime.h>
#include <hip/hip_bf16.h>

typedef unsigned int u32;
typedef unsigned short u16;

using bf16x8 = __attribute__((ext_vector_type(8))) short;
using f32x4  = __attribute__((ext_vector_type(4))) float;

#define DEVI static __device__ __forceinline__

DEVI u16 f2bf(float f) {
  __hip_bfloat16 h = __float2bfloat16(f);  // RNE
  union { __hip_bfloat16 h; u16 u; } v; v.h = h;
  return v.u;
}

// ---------------------------------------------------------------------------
// Kernel 1: select + convert x[:, :2048, :] (f32) -> Xb bf16 [8192][2048]
// Router is identity: softmax over size-1 axis == 1.0, top_k of equal scores
// returns indices 0..2047 (stable tie-break). So selected tokens are the
// first 2048 of each batch.
// ---------------------------------------------------------------------------
__global__ void k_convert_x(const float* __restrict__ x, u16* __restrict__ xb) {
  int idx = blockIdx.x * blockDim.x + threadIdx.x;   // 4 elems per thread
  size_t e = (size_t)idx * 4;
  int row = (int)(e >> 11);        // 0..8191
  int d   = (int)(e & 2047);
  int b = row >> 11, t = row & 2047;
  const float4 v = *reinterpret_cast<const float4*>(
      x + ((size_t)(b * 4096 + t) * 2048 + d));
  ushort4 o;
  o.x = f2bf(v.x); o.y = f2bf(v.y); o.z = f2bf(v.z); o.w = f2bf(v.w);
  *reinterpret_cast<ushort4*>(xb + (size_t)row * 2048 + d) = o;
}

// ---------------------------------------------------------------------------
// Kernel 2: transpose + convert  in[R][C] f32  ->  out[C][R] bf16
// 64x64 tiles via LDS (padded to stride 66 to break bank conflicts).
// ---------------------------------------------------------------------------
__global__ void k_transpose_bf16(const float* __restrict__ in,
                                 u16* __restrict__ out, int R, int C) {
  __shared__ u16 lds[64][66];
  const int t = threadIdx.x;        // 256
  const int tile_r = blockIdx.y * 64;
  const int tile_c = blockIdx.x * 64;
  const int cc = (t & 15) * 4;
  const int r0 = t >> 4;
#pragma unroll
  for (int i = 0; i < 4; ++i) {
    int r = r0 + i * 16;
    const float4 v = *reinterpret_cast<const float4*>(
        in + (size_t)(tile_r + r) * C + tile_c + cc);
    lds[r][cc]     = f2bf(v.x);
    lds[r][cc + 1] = f2bf(v.y);
    lds[r][cc + 2] = f2bf(v.z);
    lds[r][cc + 3] = f2bf(v.w);
  }
  __syncthreads();
  const int rr = (t & 15) * 4;
  const int c0 = t >> 4;
#pragma unroll
  for (int i = 0; i < 4; ++i) {
    int c = c0 + i * 16;
    ushort4 o;
    o.x = lds[rr][c]; o.y = lds[rr + 1][c];
    o.z = lds[rr + 2][c]; o.w = lds[rr + 3][c];
    *reinterpret_cast<ushort4*>(out + (size_t)(tile_c + c) * R + tile_r + rr) = o;
  }
}

// ---------------------------------------------------------------------------
// Kernel 3: m97-structure bf16 GEMM, B^T input.
//   C[M][N] = A[M][K] * B^T  (B stored [N][K]),  + bias[col]
//   DO_GELU=1: apply tanh-gelu, store bf16. DO_GELU=0: store f32.
// 128x128 tile, BK=32, 4 waves (2x2), 16x16x32 MFMA, global_load_lds x16.
// ---------------------------------------------------------------------------
#define GLDS16(g, l)                                                          \
  __builtin_amdgcn_global_load_lds(                                           \
      (const __attribute__((address_space(1))) u32*)(g),                      \
      (__attribute__((address_space(3))) u32*)(l), 16, 0, 0)

template <int DO_GELU>
__global__ __launch_bounds__(256) void k_gemm_bt(
    const u16* __restrict__ A, const u16* __restrict__ B,
    const float* __restrict__ bias, void* __restrict__ Cout,
    int M, int N, int K, int nbn) {
  __shared__ __align__(16) u16 As[128 * 32];
  __shared__ __align__(16) u16 Bs[128 * 32];

  // XCD-aware bijective swizzle (grid % 8 == 0 for both launches)
  const int nwg = gridDim.x;
  const int bid = blockIdx.x;
  const int qq8 = nwg >> 3;
  const int wg  = (bid & 7) * qq8 + (bid >> 3);
  const int bm = wg / nbn, bn = wg % nbn;

  const int t = threadIdx.x;
  const int wave = t >> 6, lane = t & 63;
  const int wr = wave >> 1, wc = wave & 1;
  const int l15 = lane & 15, lhi = lane >> 4;

  const size_t arow0 = (size_t)bm * 128;
  const size_t brow0 = (size_t)bn * 128;

  const int lrow = lane >> 2;        // 0..15 row within 16-row chunk
  const int sch  = (lane & 3) * 8;   // bf16 col within BK=32

  f32x4 acc[4][4] = {};

  for (int k0 = 0; k0 < K; k0 += 32) {
    // stage A/B tiles: per wave, 2 chunks of 16 rows each (1KB per call)
#pragma unroll
    for (int i = 0; i < 2; ++i) {
      const int r = wave * 32 + i * 16;  // wave-uniform LDS base row
      GLDS16(A + (arow0 + r + lrow) * (size_t)K + k0 + sch, As + r * 32);
      GLDS16(B + (brow0 + r + lrow) * (size_t)K + k0 + sch, Bs + r * 32);
    }
    __syncthreads();

    bf16x8 af[4], bf_[4];
#pragma unroll
    for (int i = 0; i < 4; ++i)
      af[i] = *reinterpret_cast<const bf16x8*>(
          As + (wr * 64 + i * 16 + l15) * 32 + lhi * 8);
#pragma unroll
    for (int j = 0; j < 4; ++j)
      bf_[j] = *reinterpret_cast<const bf16x8*>(
          Bs + (wc * 64 + j * 16 + l15) * 32 + lhi * 8);
#pragma unroll
    for (int i = 0; i < 4; ++i)
#pragma unroll
      for (int j = 0; j < 4; ++j)
        acc[i][j] = __builtin_amdgcn_mfma_f32_16x16x32_bf16(
            af[i], bf_[j], acc[i][j], 0, 0, 0);
    __syncthreads();
  }

  // epilogue: C/D layout col = lane&15 (B index), row = (lane>>4)*4 + reg (A index)
#pragma unroll
  for (int i = 0; i < 4; ++i) {
    const int row = (int)arow0 + wr * 64 + i * 16 + lhi * 4;
#pragma unroll
    for (int j = 0; j < 4; ++j) {
      const int col = (int)brow0 + wc * 64 + j * 16 + l15;
      const float bb = bias[col];
#pragma unroll
      for (int r = 0; r < 4; ++r) {
        float v = acc[i][j][r] + bb;
        if (DO_GELU) {
          // gelu(v) = v * sigmoid(2*0.7978845608*(v + 0.044715 v^3))
          float u2 = v * (1.5957691216f + 0.0713548162f * v * v);
          float g  = v / (1.f + __expf(-u2));
          ((u16*)Cout)[(size_t)(row + r) * N + col] = f2bf(g);
        } else {
          ((float*)Cout)[(size_t)(row + r) * N + col] = v;
        }
      }
    }
  }
}

// ---------------------------------------------------------------------------
extern "C" void kernel_launch(void* const* d_in, const int* in_sizes, int n_in,
                              void* d_out, int out_size, void* d_ws,
                              size_t ws_size, hipStream_t stream) {
  const float* x  = (const float*)d_in[0];
  // d_in[1] = Wp, d_in[2] = bp : router is identity, unused.
  const float* W1 = (const float*)d_in[3];
  const float* b1 = (const float*)d_in[4];
  const float* W2 = (const float*)d_in[5];
  const float* b2 = (const float*)d_in[6];
  float* out = (float*)d_out;

  char* ws = (char*)d_ws;
  u16* Xb  = (u16*)(ws);                       // 8192x2048 bf16 = 32 MiB
  u16* W1T = (u16*)(ws + 33554432);            // 8192x2048 bf16 = 32 MiB
  u16* W2T = (u16*)(ws + 67108864);            // 2048x8192 bf16 = 32 MiB
  u16* H   = (u16*)(ws + 100663296);           // 8192x8192 bf16 = 128 MiB

  // 1. select + convert x
  k_convert_x<<<16384, 256, 0, stream>>>(x, Xb);
  // 2. transpose-convert weights: W1 [2048][8192] -> W1T [8192][2048]
  k_transpose_bf16<<<dim3(8192 / 64, 2048 / 64), 256, 0, stream>>>(W1, W1T, 2048, 8192);
  //    W2 [8192][2048] -> W2T [2048][8192]
  k_transpose_bf16<<<dim3(2048 / 64, 8192 / 64), 256, 0, stream>>>(W2, W2T, 8192, 2048);
  // 3. H = gelu(Xb @ W1 + b1)   : M=8192 N=8192 K=2048, 64x64=4096 blocks
  k_gemm_bt<1><<<4096, 256, 0, stream>>>(Xb, W1T, b1, (void*)H, 8192, 8192, 2048, 64);
  // 4. out = H @ W2 + b2        : M=8192 N=2048 K=8192, 64x16=1024 blocks
  k_gemm_bt<0><<<1024, 256, 0, stream>>>(H, W2T, b2, (void*)out, 8192, 2048, 8192, 16);
}

// Round 2
// 561.970 us; speedup vs baseline: 1.7564x; 1.7564x over previous
//
#include <hip/hip_runtime.h>
#include <hip/hip_bf16.h>

typedef unsigned int u32;
typedef unsigned short u16;

using bf16x8 = __attribute__((ext_vector_type(8))) short;
using f32x4  = __attribute__((ext_vector_type(4))) float;

#define DEVI static __device__ __forceinline__

DEVI u16 f2bf(float f) {
  __hip_bfloat16 h = __float2bfloat16(f);  // RNE
  union { __hip_bfloat16 h; u16 u; } v; v.h = h;
  return v.u;
}

// ---------------------------------------------------------------------------
// Kernel 1: select + convert x[:, :2048, :] (f32) -> Xb bf16 [8192][2048]
// Router is identity: softmax over size-1 axis == 1.0; top_k of equal scores
// returns indices 0..2047 (stable tie-break).
// ---------------------------------------------------------------------------
__global__ void k_convert_x(const float* __restrict__ x, u16* __restrict__ xb) {
  int idx = blockIdx.x * blockDim.x + threadIdx.x;   // 4 elems per thread
  size_t e = (size_t)idx * 4;
  int row = (int)(e >> 11);        // 0..8191
  int d   = (int)(e & 2047);
  int b = row >> 11, t = row & 2047;
  const float4 v = *reinterpret_cast<const float4*>(
      x + ((size_t)(b * 4096 + t) * 2048 + d));
  ushort4 o;
  o.x = f2bf(v.x); o.y = f2bf(v.y); o.z = f2bf(v.z); o.w = f2bf(v.w);
  *reinterpret_cast<ushort4*>(xb + (size_t)row * 2048 + d) = o;
}

// ---------------------------------------------------------------------------
// Kernel 2: transpose + convert  in[R][C] f32  ->  out[C][R] bf16
// ---------------------------------------------------------------------------
__global__ void k_transpose_bf16(const float* __restrict__ in,
                                 u16* __restrict__ out, int R, int C) {
  __shared__ u16 lds[64][66];
  const int t = threadIdx.x;        // 256
  const int tile_r = blockIdx.y * 64;
  const int tile_c = blockIdx.x * 64;
  const int cc = (t & 15) * 4;
  const int r0 = t >> 4;
#pragma unroll
  for (int i = 0; i < 4; ++i) {
    int r = r0 + i * 16;
    const float4 v = *reinterpret_cast<const float4*>(
        in + (size_t)(tile_r + r) * C + tile_c + cc);
    lds[r][cc]     = f2bf(v.x);
    lds[r][cc + 1] = f2bf(v.y);
    lds[r][cc + 2] = f2bf(v.z);
    lds[r][cc + 3] = f2bf(v.w);
  }
  __syncthreads();
  const int rr = (t & 15) * 4;
  const int c0 = t >> 4;
#pragma unroll
  for (int i = 0; i < 4; ++i) {
    int c = c0 + i * 16;
    ushort4 o;
    o.x = lds[rr][c]; o.y = lds[rr + 1][c];
    o.z = lds[rr + 2][c]; o.w = lds[rr + 3][c];
    *reinterpret_cast<ushort4*>(out + (size_t)(tile_c + c) * R + tile_r + rr) = o;
  }
}

// ---------------------------------------------------------------------------
// Kernel 3: 256x256 8-phase bf16 GEMM (T2 swizzle + T3/T4 counted vmcnt + T5).
//   C[M][N] = A[M][K] * B^T (B stored [N][K]), + bias[col]
//   BM=BN=256, BK=64, 512 threads = 8 waves (2M x 4N), per-wave 128x64 out.
//   LDS 128 KiB: A[2][256][64] + B[2][256][64] bf16, double-buffered.
//   Swizzle: phys_byte = logical_byte ^ ((row&7)<<4)  (involution, 128B rows).
//   global_load_lds writes linearly; the global SOURCE is pre-swizzled.
// ---------------------------------------------------------------------------
#define GLDS16(g, l)                                                          \
  __builtin_amdgcn_global_load_lds(                                           \
      (const __attribute__((address_space(1))) u32*)(g),                      \
      (__attribute__((address_space(3))) u32*)(l), 16, 0, 0)

template <int DO_GELU>
__global__ __launch_bounds__(512, 2) void k_gemm8(
    const u16* __restrict__ A, const u16* __restrict__ B,
    const float* __restrict__ bias, void* __restrict__ Cout,
    int M, int N, int K, int nbn) {
  // [0..16383]        : A buf p=0   (u16 units; 32KB)
  // [16384..32767]    : A buf p=1
  // [32768..49151]    : B buf p=0
  // [49152..65535]    : B buf p=1
  __shared__ __align__(64) u16 lds[65536];

  // XCD-aware bijective swizzle (grid % 8 == 0 for both launches)
  const int nwg = gridDim.x;
  const int bid = blockIdx.x;
  const int wg  = (bid & 7) * (nwg >> 3) + (bid >> 3);
  const int bm = wg / nbn, bn = wg % nbn;

  const int tid  = threadIdx.x;
  const int w    = tid >> 6, lane = tid & 63;
  const int wr   = w >> 2, wcol = w & 3;     // wave tile: rows wr*128, cols wcol*64
  const int l15  = lane & 15, lhi = lane >> 4;

  const size_t arow0 = (size_t)bm * 256;
  const size_t brow0 = (size_t)bn * 256;

  // ---- staging: lane covers phys 16B chunk -> logical col chunk is XOR'd
  const int srow  = tid >> 3;                                  // 0..63
  const int scolb = ((tid & 7) * 16) ^ ((srow & 7) << 4);      // byte col in row
  const u16* pA = A + (arow0 + srow) * (size_t)K + (scolb >> 1);
  const u16* pB = B + (brow0 + srow) * (size_t)K + (scolb >> 1);
  const int wA = w * 512;  // u16 offset of this wave's 1KB stage slot

  // ---- fragment-read bases (bytes), swizzle folded in
  const u32 arow_b = (u32)((wr * 128 + l15) * 128);
  const u32 brow_b = (u32)((wcol * 64 + l15) * 128);
  const u32 axor   = (u32)((lhi * 16) ^ ((l15 & 7) << 4));
  const char* ldsb = (const char*)lds;

  f32x4 acc[8][4] = {};
  const int nk = K >> 6;

#define STAGE_PAIR(KT, PB, C)                                                 \
  do {                                                                        \
    GLDS16(pA + (size_t)(KT) * 64 + (size_t)(C) * 64 * (size_t)K,             \
           lds + (PB) * 16384 + (C) * 4096 + wA);                             \
    GLDS16(pB + (size_t)(KT) * 64 + (size_t)(C) * 64 * (size_t)K,             \
           lds + 32768 + (PB) * 16384 + (C) * 4096 + wA);                     \
  } while (0)

#define READ_A(MH, ABASE)                                                     \
  _Pragma("unroll") for (int m2 = 0; m2 < 4; ++m2)                            \
  _Pragma("unroll") for (int kk = 0; kk < 2; ++kk)                            \
    afr[m2][kk] = *(const bf16x8*)(ldsb + (ABASE) + arow_b +                  \
                                   ((MH)*4 + m2) * 2048 + (axor ^ (kk << 6)));

#define READ_B(DST, NH, BBASE)                                                \
  _Pragma("unroll") for (int n2 = 0; n2 < 2; ++n2)                            \
  _Pragma("unroll") for (int kk = 0; kk < 2; ++kk)                            \
    DST[n2][kk] = *(const bf16x8*)(ldsb + (BBASE) + brow_b +                  \
                                   ((NH)*2 + n2) * 2048 + (axor ^ (kk << 6)));

#define MFMA_Q(MH, NH, BREG)                                                  \
  _Pragma("unroll") for (int m2 = 0; m2 < 4; ++m2)                            \
  _Pragma("unroll") for (int n2 = 0; n2 < 2; ++n2)                            \
  _Pragma("unroll") for (int kk = 0; kk < 2; ++kk)                            \
    acc[(MH)*4 + m2][(NH)*2 + n2] = __builtin_amdgcn_mfma_f32_16x16x32_bf16(  \
        afr[m2][kk], BREG[n2][kk], acc[(MH)*4 + m2][(NH)*2 + n2], 0, 0, 0);

  // ---- prologue: kt0 fully, kt1 pairs 0,1. Steady-state invariant:
  //      4 loads (next kt's pairs 0,1) in flight at iteration entry.
  STAGE_PAIR(0, 0, 0); STAGE_PAIR(0, 0, 1);
  STAGE_PAIR(0, 0, 2); STAGE_PAIR(0, 0, 3);
  if (nk > 1) {
    STAGE_PAIR(1, 1, 0); STAGE_PAIR(1, 1, 1);
    asm volatile("s_waitcnt vmcnt(4)" ::: "memory");
  } else {
    asm volatile("s_waitcnt vmcnt(0)" ::: "memory");
  }
  __builtin_amdgcn_s_barrier();

  for (int kt = 0; kt < nk; ++kt) {
    const int p = kt & 1;
    const u32 abase = (u32)p * 32768u;            // bytes
    const u32 bbase = 65536u + (u32)p * 32768u;   // bytes
    bf16x8 afr[4][2], b0[2][2], b1[2][2];

    // phase 0: quadrant (mh0, nh0)
    READ_A(0, abase);
    READ_B(b0, 0, bbase);
    if (kt + 1 < nk) STAGE_PAIR(kt + 1, p ^ 1, 2);
    __builtin_amdgcn_s_barrier();
    __builtin_amdgcn_s_setprio(1);
    MFMA_Q(0, 0, b0);
    __builtin_amdgcn_s_setprio(0);
    __builtin_amdgcn_s_barrier();

    // phase 1: (mh0, nh1)
    READ_B(b1, 1, bbase);
    if (kt + 1 < nk) STAGE_PAIR(kt + 1, p ^ 1, 3);
    __builtin_amdgcn_s_barrier();
    __builtin_amdgcn_s_setprio(1);
    MFMA_Q(0, 1, b1);
    __builtin_amdgcn_s_setprio(0);
    __builtin_amdgcn_s_barrier();

    // phase 2: (mh1, nh1) — reuse b1
    READ_A(1, abase);
    __builtin_amdgcn_s_barrier();
    __builtin_amdgcn_s_setprio(1);
    MFMA_Q(1, 1, b1);
    __builtin_amdgcn_s_setprio(0);
    __builtin_amdgcn_s_barrier();

    // phase 3: (mh1, nh0) — reuse b0, no new LDS reads
    __builtin_amdgcn_s_setprio(1);
    MFMA_Q(1, 0, b0);
    __builtin_amdgcn_s_setprio(0);
    __builtin_amdgcn_s_barrier();

    // boundary: buf p is now dead (all waves past last consumer barrier).
    // Issue kt+2 pairs 0,1 into buf p, then wait for kt+1's 8 loads only.
    if (kt + 2 < nk) {
      STAGE_PAIR(kt + 2, p, 0); STAGE_PAIR(kt + 2, p, 1);
      asm volatile("s_waitcnt vmcnt(4)" ::: "memory");
    } else {
      asm volatile("s_waitcnt vmcnt(0)" ::: "memory");
    }
    __builtin_amdgcn_s_barrier();
  }

  // ---- epilogue: C/D layout col = lane&15, row = (lane>>4)*4 + reg
#pragma unroll
  for (int m = 0; m < 8; ++m) {
    const int row = (int)arow0 + wr * 128 + m * 16 + lhi * 4;
#pragma unroll
    for (int n = 0; n < 4; ++n) {
      const int col = (int)brow0 + wcol * 64 + n * 16 + l15;
      const float bb = bias[col];
#pragma unroll
      for (int r = 0; r < 4; ++r) {
        float v = acc[m][n][r] + bb;
        if (DO_GELU) {
          float u2 = v * (1.5957691216f + 0.0713548162f * v * v);
          float g  = v / (1.f + __expf(-u2));
          ((u16*)Cout)[(size_t)(row + r) * N + col] = f2bf(g);
        } else {
          ((float*)Cout)[(size_t)(row + r) * N + col] = v;
        }
      }
    }
  }
#undef STAGE_PAIR
#undef READ_A
#undef READ_B
#undef MFMA_Q
}

// ---------------------------------------------------------------------------
extern "C" void kernel_launch(void* const* d_in, const int* in_sizes, int n_in,
                              void* d_out, int out_size, void* d_ws,
                              size_t ws_size, hipStream_t stream) {
  const float* x  = (const float*)d_in[0];
  // d_in[1] = Wp, d_in[2] = bp : router is identity, unused.
  const float* W1 = (const float*)d_in[3];
  const float* b1 = (const float*)d_in[4];
  const float* W2 = (const float*)d_in[5];
  const float* b2 = (const float*)d_in[6];
  float* out = (float*)d_out;

  char* ws = (char*)d_ws;
  u16* Xb  = (u16*)(ws);                       // 8192x2048 bf16 = 32 MiB
  u16* W1T = (u16*)(ws + 33554432);            // 8192x2048 bf16 = 32 MiB
  u16* W2T = (u16*)(ws + 67108864);            // 2048x8192 bf16 = 32 MiB
  u16* H   = (u16*)(ws + 100663296);           // 8192x8192 bf16 = 128 MiB

  // 1. select + convert x
  k_convert_x<<<16384, 256, 0, stream>>>(x, Xb);
  // 2. transpose-convert weights
  k_transpose_bf16<<<dim3(8192 / 64, 2048 / 64), 256, 0, stream>>>(W1, W1T, 2048, 8192);
  k_transpose_bf16<<<dim3(2048 / 64, 8192 / 64), 256, 0, stream>>>(W2, W2T, 8192, 2048);
  // 3. H = gelu(Xb @ W1^T^T + b1) : M=8192 N=8192 K=2048, 32x32 = 1024 blocks
  k_gemm8<1><<<1024, 512, 0, stream>>>(Xb, W1T, b1, (void*)H, 8192, 8192, 2048, 32);
  // 4. out = H @ W2^T^T + b2      : M=8192 N=2048 K=8192, 32x8 = 256 blocks
  k_gemm8<0><<<256, 512, 0, stream>>>(H, W2T, b2, (void*)out, 8192, 2048, 8192, 8);
}